// Round 14
// baseline (169.759 us; speedup 1.0000x reference)
//
#include <hip/hip_runtime.h>
#include <math.h>

#define NPTS 32768
#define NIMG 32          // B*C = 8*4
#define CAPP 192         // per-tile point capacity (mean ~66, max ~126)
#define CAPC 57          // per-cell entry capacity (mean ~18, max ~46); odd -> bank-conflict-free
#define SCALE ((float)(256.0 / (2.0 * M_PI)))

typedef __attribute__((ext_vector_type(8))) short short8b;   // 8 bf16 (4 VGPRs)
typedef __attribute__((ext_vector_type(4))) float f32x4;

// float -> bf16 (RNE)
static __device__ __forceinline__ unsigned short f2bf(float x) {
    unsigned u = __float_as_uint(x);
    return (unsigned short)((u + 0x7fffu + ((u >> 16) & 1u)) >> 16);
}

static __device__ __forceinline__ double bessel_i0d(double x) {
    double hx2 = 0.25 * x * x;
    double t = 1.0, s = 1.0;
#pragma unroll
    for (int m = 1; m <= 40; ++m) {
        t *= hx2 * (1.0 / ((double)m * (double)m));
        s += t;
    }
    return s;
}

static __device__ __forceinline__ float bessel_i0f(float x) {
    float hx2 = 0.25f * x * x;
    float t = 1.0f, s = 1.0f;
#pragma unroll
    for (int m = 1; m <= 30; ++m) {
        t *= hx2 * (1.0f / ((float)m * (float)m));
        s += t;
    }
    return s;
}

// ---------- K1: zero tileCount + barrier counter ----------
__global__ void k_init(unsigned* __restrict__ tileCount, unsigned* __restrict__ bar) {
    if (blockIdx.x < 64) tileCount[blockIdx.x * 256 + threadIdx.x] = 0u;
    else if (threadIdx.x == 0) *bar = 0u;
}

// ---------- K2: fused front end (verbatim from round 11) ----------
__global__ __launch_bounds__(256) void k_front(
        const float* __restrict__ coords, const float* __restrict__ values,
        unsigned short* __restrict__ Sfrag, float* __restrict__ wxy,
        unsigned* __restrict__ tileCount, unsigned* __restrict__ bins,
        float* __restrict__ vt) {
    __shared__ float tile[32][257];                 // transpose role
    __shared__ double ere[256], eim[256];           // setup role
    __shared__ float ax[128];
    __shared__ float2 sSh[256];
    int blk = blockIdx.x;
    int t = threadIdx.x;

    if (blk < 128) {
        // ---- prep: weights + 8x8 tile binning ----
        int k = blk * 256 + t;
        const float inv_i0a = 1.0f / bessel_i0f(14.04f);  // constant-folds
        float2 cv = *(const float2*)&coords[2 * k];
        float gmx = cv.x * SCALE;
        float gmy = cv.y * SCALE;
        float bxf = floorf(gmx - 3.0f), byf = floorf(gmy - 3.0f);
        float wl[12];
#pragma unroll
        for (int j = 0; j < 6; ++j) {
            float ux = gmx - (bxf + (float)(j + 1));
            float rx = ux * (1.0f / 3.0f);
            float argx = 1.0f - rx * rx;
            wl[j] = (argx > 0.0f) ? bessel_i0f(14.04f * sqrtf(argx)) * inv_i0a : 0.0f;
            float uy = gmy - (byf + (float)(j + 1));
            float ry = uy * (1.0f / 3.0f);
            float argy = 1.0f - ry * ry;
            wl[6 + j] = (argy > 0.0f) ? bessel_i0f(14.04f * sqrtf(argy)) * inv_i0a : 0.0f;
        }
        float4* wp = (float4*)&wxy[k * 12];
        wp[0] = *(const float4*)&wl[0];
        wp[1] = *(const float4*)&wl[4];
        wp[2] = *(const float4*)&wl[8];
        int x0 = (((int)bxf) + 1 + 512) & 255;
        int y0 = (((int)byf) + 1 + 512) & 255;
        int tx0 = x0 >> 3, tx1 = ((x0 + 5) & 255) >> 3;
        int ty0 = y0 >> 3, ty1 = ((y0 + 5) & 255) >> 3;
        int nx = (tx1 == tx0) ? 1 : 2;
        int ny = (ty1 == ty0) ? 1 : 2;
        int txs[2] = {tx0, tx1}, tys[2] = {ty0, ty1};
        for (int i = 0; i < nx; ++i)
            for (int j = 0; j < ny; ++j) {
                int tl = txs[i] * 32 + tys[j];
                unsigned ex = (unsigned)((x0 - 8 * txs[i] + 256) & 255);
                unsigned ey = (unsigned)((y0 - 8 * tys[j] + 256) & 255);
                unsigned pos = atomicAdd(&tileCount[tl * 16], 1u);   // line-padded
                if (pos < CAPP) bins[tl * CAPP + pos] = ((unsigned)k << 16) | (ex << 8) | ey;
            }
    } else if (blk < 256) {
        // ---- transpose values -> vt[k][img] ----
        int kbase = (blk - 128) * 256;
        for (int img = 0; img < 32; ++img)
            tile[img][t] = values[img * NPTS + kbase + t];
        __syncthreads();
        int img = t & 31;
        int k0 = t >> 5;                   // 0..7
        for (int r = 0; r < 32; ++r) {
            int kl = k0 + r * 8;           // 0..255
            vt[(kbase + kl) * 32 + img] = tile[img][kl];
        }
    } else {
        // ---- setup: S table + MFMA fragment tables ----
        double ang = (double)t * (2.0 * M_PI / 256.0);
        ere[t] = cos(ang);
        eim[t] = sin(ang);
        if (t < 128) {
            double i0a = bessel_i0d(14.04);
            double om = ((double)t - 63.5) * (1.0 / 256.0);
            double pj = M_PI * 6.0 * om;
            double tt = sqrt(14.04 * 14.04 - pj * pj);   // always real here
            double kbft = 6.0 * (sinh(tt) / tt) / i0a;
            ax[t] = (float)(1.0 / kbft);                 // apodization 1D
        }
        __syncthreads();
        double re = 0.0, im = 0.0;
        for (int x = 0; x < 128; ++x) {
            int ph = (x * t) & 255;                      // exact phase reduction
            re += (double)ax[x] * ere[ph];
            im += (double)ax[x] * eim[ph];
        }
        sSh[t] = make_float2((float)re, (float)im);
        __syncthreads();
        // Sfrag: [var(re,im,-im)][tile8][kstep8][lane64][elem8]
        for (int idx = t; idx < 32768; idx += 256) {
            int i   = idx & 7;
            int ln  = (idx >> 3) & 63;
            int ks  = (idx >> 9) & 7;
            int tl  = idx >> 12;
            int s = (32 * ks + 8 * (ln >> 4) + i - 2 * (16 * tl + (ln & 15))) & 255;
            float2 sv = sSh[s];
            Sfrag[idx]         = f2bf(sv.x);
            Sfrag[32768 + idx] = f2bf(sv.y);
            Sfrag[65536 + idx] = f2bf(-sv.y);
        }
    }
}

// ---------- K3: gather (2 tiles/block) -> grid barrier -> MFMA spectral ----------
__global__ __launch_bounds__(256, 2) void k_tail(
        const float* __restrict__ wxy, const float* __restrict__ vt,
        const unsigned* __restrict__ tileCount, const unsigned* __restrict__ bins,
        unsigned short* __restrict__ Gt, const unsigned short* __restrict__ Sfrag,
        unsigned* __restrict__ bar, float* __restrict__ out) {
    __shared__ __align__(16) char smem[20736];
    int t = threadIdx.x;
    int blk = blockIdx.x;

    // ================= gather phase: tiles blk and blk+512 =================
    {
        unsigned* cnt = (unsigned*)smem;                       // 64
        unsigned* lists = cnt + 64;                            // 64*CAPC
        unsigned* bsh = lists + 64 * CAPC;                     // CAPP
        unsigned short (*gsh)[40] = (unsigned short(*)[40])(bsh + CAPP);  // 64x40
        for (int ti = 0; ti < 2; ++ti) {
            int tile = blk + ti * 512;
            int TX = tile >> 5, TY = tile & 31;
            __syncthreads();
            if (t < 64) cnt[t] = 0u;
            unsigned n = tileCount[tile * 16];
            if (n > CAPP) n = CAPP;
            for (int p = t; p < (int)n; p += 256) bsh[p] = bins[tile * CAPP + p];
            __syncthreads();
            // stage A: build per-cell entry lists
            int total = (int)n * 6;
            for (int task = t; task < total; task += 256) {
                int pi = task / 6;
                int jx = task - pi * 6;
                unsigned en = bsh[pi];
                int ex = (int)((en >> 8) & 255u);
                int ey = (int)(en & 255u);
                if (((ex + jx) & 255) < 8) {
                    unsigned k = en >> 16;
                    float wxv = wxy[k * 12 + jx];
                    int lx = ((ex + jx) & 7) << 3;
                    unsigned kq = k << 16;
                    int jy0, jy1;
                    if (ey <= 7) { jy0 = 0; jy1 = (7 - ey < 5) ? 7 - ey : 5; }
                    else         { jy0 = 256 - ey; jy1 = 5; }
                    for (int jy = jy0; jy <= jy1; ++jy) {
                        float w = wxv * wxy[k * 12 + 6 + jy];
                        unsigned q = (unsigned)(w * 65535.0f + 0.5f);
                        if (q > 65535u) q = 65535u;
                        int cl = lx | ((ey + jy) & 7);
                        unsigned pos = atomicAdd(&cnt[cl], 1u);    // native u32 LDS atomic
                        if (pos < CAPC) lists[cl * CAPC + pos] = kq | q;
                    }
                }
            }
            __syncthreads();
            // stage B: thread owns (cell c, 8 images)
            int c = t >> 2;
            int ib = (t & 3) * 8;
            unsigned nc = cnt[c];
            if (nc > CAPC) nc = CAPC;
            float acc0 = 0, acc1 = 0, acc2 = 0, acc3 = 0, acc4 = 0, acc5 = 0, acc6 = 0, acc7 = 0;
            for (unsigned e = 0; e < nc; ++e) {
                unsigned en = lists[c * CAPC + e];             // broadcast within quad
                float w = (float)(en & 0xFFFFu) * (1.0f / 65535.0f);
                const float* vp = &vt[(en >> 16) * 32 + ib];
                float4 va = *(const float4*)vp;
                float4 vb = *(const float4*)(vp + 4);
                acc0 += w * va.x; acc1 += w * va.y; acc2 += w * va.z; acc3 += w * va.w;
                acc4 += w * vb.x; acc5 += w * vb.y; acc6 += w * vb.z; acc7 += w * vb.w;
            }
            {
                unsigned short* gp = &gsh[c][ib];
                gp[0] = f2bf(acc0); gp[1] = f2bf(acc1); gp[2] = f2bf(acc2); gp[3] = f2bf(acc3);
                gp[4] = f2bf(acc4); gp[5] = f2bf(acc5); gp[6] = f2bf(acc6); gp[7] = f2bf(acc7);
            }
            __syncthreads();
            // writeout: thread t -> (img = t>>3, vrow = t&7): 16B contiguous store
            {
                int img = t >> 3;
                int vr = t & 7;
                short8b row;
#pragma unroll
                for (int uu = 0; uu < 8; ++uu)
                    row[uu] = (short)gsh[(uu << 3) | vr][img];
                *(short8b*)&Gt[img * 65536 + (((TY << 3) + vr) << 8) + (TX << 3)] = row;
            }
        }
    }

    // ================= software grid barrier (512 blocks co-resident by launch_bounds) ====
    __threadfence();                      // publish Gt (device-scope release)
    __syncthreads();
    if (t == 0) {
        atomicAdd(bar, 1u);
        while (__hip_atomic_load(bar, __ATOMIC_RELAXED, __HIP_MEMORY_SCOPE_AGENT) < 512u)
            __builtin_amdgcn_s_sleep(1);
        __threadfence();                  // acquire: invalidate stale caches
    }
    __syncthreads();

    // ================= MFMA spectral phase (blocks 0..255) =================
    if (blk < 256) {
        unsigned short* T1 = (unsigned short*)smem;   // [2][16][264] = 16896B
        // XCD-aware decode: blocks with same (blk&7) share an img-group -> L2 reuse
        int g = blk & 7;
        int img = g * 4 + ((blk >> 3) & 3);
        int band = blk >> 5;
        int lane = t & 63;
        int w = t >> 6;                    // wave 0..3
        int g4 = lane >> 4;                // k-subgroup
        int l15 = lane & 15;

        // ---- stage 1: var = w>>1, v-tiles (w&1)+2j ----
        {
            int var = w >> 1;
            const unsigned short* sf = Sfrag + var * 32768 + band * 4096 + lane * 8;
            short8b a[8];
#pragma unroll
            for (int ks = 0; ks < 8; ++ks)
                a[ks] = *(const short8b*)(sf + ks * 512);
            const unsigned short* gimg = Gt + img * 65536 + 8 * g4;
#pragma unroll
            for (int j = 0; j < 8; ++j) {
                int vtile = (w & 1) + j * 2;
                int v0 = vtile * 16;
                const unsigned short* gb = gimg + (v0 + l15) * 256;
                f32x4 acc = {0.f, 0.f, 0.f, 0.f};
#pragma unroll
                for (int ks = 0; ks < 8; ++ks) {
                    short8b b = *(const short8b*)(gb + ks * 32);
                    acc = __builtin_amdgcn_mfma_f32_16x16x32_bf16(a[ks], b, acc, 0, 0, 0);
                }
                int vcol = v0 + l15;
#pragma unroll
                for (int r = 0; r < 4; ++r) {
                    int p = g4 * 4 + r;
                    T1[var * 4224 + p * 264 + (vcol ^ ((p & 7) << 3))] = f2bf(acc[r]);
                }
            }
        }
        __syncthreads();

        // ---- stage 2: q-tiles w and w+4 ----
        int b_ = img >> 2, c_ = img & 3;
        int obase = ((b_ ^ 4) * 4 + (c_ ^ 2)) * 128;
        int swz = (l15 & 7) << 3;
#pragma unroll
        for (int jj = 0; jj < 2; ++jj) {
            int qt = w + jj * 4;
            const unsigned short* sfq = Sfrag + qt * 4096 + lane * 8;
            f32x4 accR = {0.f, 0.f, 0.f, 0.f}, accI = {0.f, 0.f, 0.f, 0.f};
#pragma unroll
            for (int ks = 0; ks < 8; ++ks) {
                int vidx = (32 * ks + 8 * g4) ^ swz;
                short8b aR = *(const short8b*)&T1[0 * 4224 + l15 * 264 + vidx];
                short8b aI = *(const short8b*)&T1[1 * 4224 + l15 * 264 + vidx];
                short8b bR = *(const short8b*)(sfq + ks * 512);
                short8b bI = *(const short8b*)(sfq + 32768 + ks * 512);
                short8b bN = *(const short8b*)(sfq + 65536 + ks * 512);
                accR = __builtin_amdgcn_mfma_f32_16x16x32_bf16(aR, bR, accR, 0, 0, 0);
                accR = __builtin_amdgcn_mfma_f32_16x16x32_bf16(aI, bN, accR, 0, 0, 0);
                accI = __builtin_amdgcn_mfma_f32_16x16x32_bf16(aR, bI, accI, 0, 0, 0);
                accI = __builtin_amdgcn_mfma_f32_16x16x32_bf16(aI, bR, accI, 0, 0, 0);
            }
            int q = qt * 16 + l15;
#pragma unroll
            for (int r = 0; r < 4; ++r) {
                int p = band * 16 + g4 * 4 + r;
                float re = accR[r], im = accI[r];
                out[((obase + (p ^ 64)) << 7) + (q ^ 64)] = sqrtf(re * re + im * im);
            }
        }
    }
}

extern "C" void kernel_launch(void* const* d_in, const int* in_sizes, int n_in,
                              void* d_out, int out_size, void* d_ws, size_t ws_size,
                              hipStream_t stream) {
    const float* values = (const float*)d_in[0];   // [8,4,32768] f32
    const float* coords = (const float*)d_in[1];   // [32768,2] f32

    char* ws = (char*)d_ws;
    // layout (peak ~10.6 MB):
    unsigned short* Sfrag = (unsigned short*)(ws + 0);          // 192 KB
    unsigned* tileCount   = (unsigned*)(ws + 196608);           // 64 KB  [1024*16] line-padded
    float*    wxy         = (float*)(ws + 262144);              // 1.5 MB [32768*12]
    unsigned* bins        = (unsigned*)(ws + 1835008);          // 768 KB [1024*CAPP]
    unsigned short* Gt    = (unsigned short*)(ws + 2621440);    // 4 MB  [32][256v][256u] bf16
    float*    vt          = (float*)(ws + 6815744);             // 4 MB  [32768][32]
    unsigned* bar         = (unsigned*)(ws + 11010048);         // 4 B

    k_init<<<65, 256, 0, stream>>>(tileCount, bar);
    k_front<<<257, 256, 0, stream>>>(coords, values, Sfrag, wxy, tileCount, bins, vt);
    k_tail<<<512, 256, 0, stream>>>(wxy, vt, tileCount, bins, Gt, Sfrag, bar, (float*)d_out);
}